// Round 3
// baseline (20538.492 us; speedup 1.0000x reference)
//
#include <hip/hip_runtime.h>
#include <hip/hip_cooperative_groups.h>

namespace cg = cooperative_groups;

// Problem constants (match reference)
#define TSTEPS 500
#define NB     64      // batch
#define NINP   64
#define NHID   1024
#define NOUTV  3
#define ALPHA_F 0.1f

// Recurrent kernel geometry
#define NWG    256     // one block per CU
#define NTHR   256     // 4 waves
#define CJ     32      // j-rows of rT per staged chunk (32*64*4B = 8KB)
#define NCH    8       // chunks per wave's j-quarter (256 j)

// r ping-pong buffer in static device memory: [2][NHID][NB] (r transposed so
// lane=b accesses are coalesced / conflict-free). 512 KB.
__device__ float g_rT[2 * NHID * NB];

// ---------------------------------------------------------------------------
// Persistent cooperative kernel: the serial T-loop.
//   wg g owns h in [g*4, g*4+4); wave w of the wg accumulates the j-quarter
//   [w*256, w*256+256) for all 4 h's (lane = batch). Cross-wave K-reduction
//   via LDS, then wave w finalizes h = g*4 + w.
//   KEY CHANGE vs R2: Whh rows live in LDS (staged once, reused x500) —
//   the per-step uniform s_load chain was the 31 us/step latency stall.
// ---------------------------------------------------------------------------
__global__ __launch_bounds__(NTHR)
void rnn_loop_kernel(const float* __restrict__ X,
                     const float* __restrict__ hidden1,
                     const float* __restrict__ Wih,
                     const float* __restrict__ Whh,
                     float* __restrict__ hid_out)   // [T][B][NHID]
{
    __shared__ float sbuf[4][2][CJ * NB];   // 4 waves x dbuf x 8KB = 64KB staging
    __shared__ float swhh[4][4 * 256];      // per wave: [4 rows][256 j] = 16KB

    const int tid  = threadIdx.x;
    const int lane = tid & 63;
    const int w    = __builtin_amdgcn_readfirstlane(tid >> 6); // wave id -> SGPR
    const int g    = blockIdx.x;
    const int hq   = g * 4;            // h-group base
    const int hmine = hq + w;          // h this wave finalizes

    const float* wih = Wih + (size_t)hmine * NINP;

    // transpose buffer for coalesced hid_out stores
    float* red2 = &sbuf[0][1][0];      // [4][64] floats, reused area

    const int jq = w * 256;            // this wave's j-quarter base

    // ---- one-time: stage this wave's Whh panel (rows hq..hq+3, cols jq..jq+255)
    {
        #pragma unroll
        for (int rr = 0; rr < 4; ++rr) {
            const float* src = Whh + (size_t)(hq + rr) * NHID + jq;
            #pragma unroll
            for (int q = 0; q < 4; ++q)
                swhh[w][rr * 256 + q * 64 + lane] = src[q * 64 + lane];
        }
    }

    // persistent state x[b=lane][hmine] in a register for the whole loop
    float x = hidden1[(size_t)lane * NHID + hmine];
    float r = tanhf(x);
    g_rT[(size_t)hmine * NB + lane] = r;
    __syncthreads();                   // swhh visible (own wave only needs it, but cheap)
    cg::this_grid().sync();

    int p = 0;

    for (int t = 0; t < TSTEPS; ++t) {
        const float* rsrc = g_rT + (size_t)p * NHID * NB;

        // stage chunk 0 of this wave's quarter (wave-private, async to LDS)
        {
            const char* gsrc = (const char*)(rsrc + (size_t)jq * NB);
            char* lbase = (char*)&sbuf[w][0][0];
            #pragma unroll
            for (int q = 0; q < 8; ++q) {
                __builtin_amdgcn_global_load_lds(
                    (const __attribute__((address_space(1))) void*)(gsrc + q * 1024 + lane * 16),
                    (__attribute__((address_space(3))) void*)(lbase + q * 1024),
                    16, 0, 0);
            }
        }

        float a0 = 0.f, a1 = 0.f, a2 = 0.f, a3 = 0.f;

        #pragma unroll 1   // keep staging/waitcnt structure intact
        for (int k = 0; k < NCH; ++k) {
            if (k + 1 < NCH) {
                // prefetch next chunk into the other buffer
                const char* gsrc = (const char*)(rsrc + (size_t)(jq + (k + 1) * CJ) * NB);
                char* lbase = (char*)&sbuf[w][(k + 1) & 1][0];
                #pragma unroll
                for (int q = 0; q < 8; ++q) {
                    __builtin_amdgcn_global_load_lds(
                        (const __attribute__((address_space(1))) void*)(gsrc + q * 1024 + lane * 16),
                        (__attribute__((address_space(3))) void*)(lbase + q * 1024),
                        16, 0, 0);
                }
                // wait for current chunk (leave the 8 just-issued in flight)
                asm volatile("s_waitcnt vmcnt(8)" ::: "memory");
            } else {
                asm volatile("s_waitcnt vmcnt(0)" ::: "memory");
            }

            const float* buf = &sbuf[w][k & 1][0];
            const float* wl  = &swhh[w][0];
            const int jb = k * CJ;     // quarter-local column base
            #pragma unroll
            for (int j4 = 0; j4 < CJ; j4 += 4) {
                // Whh from LDS: wave-uniform addr -> ds_read_b128 broadcast (free)
                float4 w0 = *(const float4*)&wl[0 * 256 + jb + j4];
                float4 w1 = *(const float4*)&wl[1 * 256 + jb + j4];
                float4 w2 = *(const float4*)&wl[2 * 256 + jb + j4];
                float4 w3 = *(const float4*)&wl[3 * 256 + jb + j4];
                // rv from LDS: lane=b, 2-way bank alias (free)
                float r0 = buf[(j4 + 0) * NB + lane];
                float r1 = buf[(j4 + 1) * NB + lane];
                float r2 = buf[(j4 + 2) * NB + lane];
                float r3 = buf[(j4 + 3) * NB + lane];
                a0 = fmaf(w0.x, r0, a0); a0 = fmaf(w0.y, r1, a0);
                a0 = fmaf(w0.z, r2, a0); a0 = fmaf(w0.w, r3, a0);
                a1 = fmaf(w1.x, r0, a1); a1 = fmaf(w1.y, r1, a1);
                a1 = fmaf(w1.z, r2, a1); a1 = fmaf(w1.w, r3, a1);
                a2 = fmaf(w2.x, r0, a2); a2 = fmaf(w2.y, r1, a2);
                a2 = fmaf(w2.z, r2, a2); a2 = fmaf(w2.w, r3, a2);
                a3 = fmaf(w3.x, r0, a3); a3 = fmaf(w3.y, r1, a3);
                a3 = fmaf(w3.z, r2, a3); a3 = fmaf(w3.w, r3, a3);
            }
        }

        // cross-wave K-reduction via LDS (all this wave's stages drained: vmcnt(0))
        {
            float* red = &sbuf[w][0][0];
            red[0 * NB + lane] = a0;
            red[1 * NB + lane] = a1;
            red[2 * NB + lane] = a2;
            red[3 * NB + lane] = a3;
        }
        __syncthreads();
        float dot = sbuf[0][0][w * NB + lane] + sbuf[1][0][w * NB + lane]
                  + sbuf[2][0][w * NB + lane] + sbuf[3][0][w * NB + lane];

        // input projection for hmine: sum_i Wih[hmine][i] * X[t][b][i]
        float xw = 0.f;
        const float4* xp = (const float4*)(X + ((size_t)t * NB + lane) * NINP);
        #pragma unroll
        for (int i = 0; i < NINP / 4; ++i) {
            float4 v = xp[i];
            xw = fmaf(wih[4 * i + 0], v.x, xw);
            xw = fmaf(wih[4 * i + 1], v.y, xw);
            xw = fmaf(wih[4 * i + 2], v.z, xw);
            xw = fmaf(wih[4 * i + 3], v.w, xw);
        }

        // leaky-integrator update + tanh (matches reference: x += a*(-x + mm))
        x = fmaf(ALPHA_F, dot + xw - x, x);
        r = tanhf(x);

        // r for next step (coalesced: 64 lanes x 4B contiguous)
        g_rT[(size_t)(p ^ 1) * NHID * NB + (size_t)hmine * NB + lane] = r;

        // transpose r through LDS so hid_out gets ONE dwordx4 store per block
        red2[w * NB + lane] = r;
        __syncthreads();
        if (w == 0) {
            float4 v;
            v.x = red2[0 * NB + lane];
            v.y = red2[1 * NB + lane];
            v.z = red2[2 * NB + lane];
            v.w = red2[3 * NB + lane];
            // hid_out[t][b=lane][hq..hq+3], 16B-aligned (hq % 4 == 0)
            *(float4*)(hid_out + ((size_t)t * NB + lane) * NHID + hq) = v;
        }

        cg::this_grid().sync();
        p ^= 1;
    }
}

// ---------------------------------------------------------------------------
// Parallel readout: one wave per (t,b). outv = r@Woutᵀ + bout; outp = pj@outv.
// ---------------------------------------------------------------------------
__global__ __launch_bounds__(256)
void out_proj_kernel(const float* __restrict__ hid,      // [T*B][NHID]
                     const float* __restrict__ perturb,  // [T*B][3][3]
                     const float* __restrict__ Wout,     // [3][NHID]
                     const float* __restrict__ bout,     // [3]
                     float* __restrict__ outv,           // [T*B][3]
                     float* __restrict__ outp)           // [T*B][3]
{
    const int gw   = (int)((blockIdx.x * blockDim.x + threadIdx.x) >> 6);
    const int lane = threadIdx.x & 63;
    if (gw >= TSTEPS * NB) return;

    const float4* r4  = (const float4*)(hid + (size_t)gw * NHID);
    const float4* w04 = (const float4*)(Wout);
    const float4* w14 = (const float4*)(Wout + NHID);
    const float4* w24 = (const float4*)(Wout + 2 * NHID);

    float s0 = 0.f, s1 = 0.f, s2 = 0.f;
    #pragma unroll
    for (int q = 0; q < 4; ++q) {
        int idx = lane * 4 + q;                 // h = idx*4 .. idx*4+3
        float4 v = r4[idx];
        float4 a = w04[idx]; s0 += v.x * a.x + v.y * a.y + v.z * a.z + v.w * a.w;
        float4 b = w14[idx]; s1 += v.x * b.x + v.y * b.y + v.z * b.z + v.w * b.w;
        float4 c = w24[idx]; s2 += v.x * c.x + v.y * c.y + v.z * c.z + v.w * c.w;
    }
    #pragma unroll
    for (int m = 1; m < 64; m <<= 1) {
        s0 += __shfl_xor(s0, m, 64);
        s1 += __shfl_xor(s1, m, 64);
        s2 += __shfl_xor(s2, m, 64);
    }
    if (lane == 0) {
        float o0 = s0 + bout[0];
        float o1 = s1 + bout[1];
        float o2 = s2 + bout[2];
        float* ov = outv + (size_t)gw * 3;
        ov[0] = o0; ov[1] = o1; ov[2] = o2;
        const float* pj = perturb + (size_t)gw * 9;
        float* op = outp + (size_t)gw * 3;
        op[0] = pj[0] * o0 + pj[1] * o1 + pj[2] * o2;
        op[1] = pj[3] * o0 + pj[4] * o1 + pj[5] * o2;
        op[2] = pj[6] * o0 + pj[7] * o1 + pj[8] * o2;
    }
}

// ---------------------------------------------------------------------------
extern "C" void kernel_launch(void* const* d_in, const int* in_sizes, int n_in,
                              void* d_out, int out_size, void* d_ws, size_t ws_size,
                              hipStream_t stream)
{
    const float* X       = (const float*)d_in[0];
    const float* perturb = (const float*)d_in[1];
    const float* hidden1 = (const float*)d_in[2];
    const float* Wih     = (const float*)d_in[3];
    const float* Whh     = (const float*)d_in[4];
    const float* Wout    = (const float*)d_in[5];
    const float* bout    = (const float*)d_in[6];

    float* out  = (float*)d_out;
    float* outv = out;
    float* outp = out + (size_t)TSTEPS * NB * NOUTV;                 // +96000
    float* hid  = out + (size_t)2 * TSTEPS * NB * NOUTV;             // +192000

    void* args[] = { (void*)&X, (void*)&hidden1, (void*)&Wih, (void*)&Whh,
                     (void*)&hid };
    hipLaunchCooperativeKernel((void*)rnn_loop_kernel, dim3(NWG), dim3(NTHR),
                               args, 0, stream);

    // readout: 32000 (t,b) waves, 4 waves/block
    out_proj_kernel<<<dim3((TSTEPS * NB) / 4), dim3(256), 0, stream>>>(
        hid, perturb, Wout, bout, outv, outp);
}

// Round 8
// 8534.466 us; speedup vs baseline: 2.4065x; 2.4065x over previous
//
#include <hip/hip_runtime.h>
#include <hip/hip_cooperative_groups.h>

// Problem constants (match reference)
#define TSTEPS 500
#define NB     64      // batch
#define NINP   64
#define NHID   1024
#define NOUTV  3
#define ALPHA_F 0.1f

// Recurrent kernel geometry
#define NWG    128     // blocks; each owns 8 h-rows
#define NTHR   256     // 4 waves; wave w handles j-quarter [w*256,(w+1)*256) for all 8 rows
#define CJ     32      // j-rows of rT per staged chunk (32*64*4B = 8KB)
#define NCH    8       // chunks per wave's j-quarter (256 j)

// Cache-policy aux bits for global_load_lds (gfx940+ CPol): SC0=1, NT=2, SC1=16.
// SC0|SC1 = bypass L1 and non-coherent L2; read from the coherent point (L3).
#define AUX_COH 0x11

// r ping-pong buffer: [2][NHID][NB], exchanged through L3 via sc1 ops. 512 KB.
__device__ float    g_rT[2 * NHID * NB];
// Fence-free barrier state (monotonic across launches; .bss zero-init once).
__device__ unsigned g_bar[TSTEPS + 1];
__device__ unsigned g_epochs[NWG];

// Fence-free grid barrier: NO device-scope release fence (that's what forced the
// per-step L2 writeback-invalidate in cg::sync). All cross-block data travels
// via sc1 (L3-coherent) ops; per-wave vmcnt(0) guarantees those acks before the
// arrive-atomic.
__device__ __forceinline__ void grid_barrier(unsigned* slot, unsigned target, int tid) {
    asm volatile("s_waitcnt vmcnt(0)" ::: "memory");   // per-wave: sc1 stores acked at L3
    __syncthreads();
    if (tid == 0) {
        __hip_atomic_fetch_add(slot, 1u, __ATOMIC_RELAXED, __HIP_MEMORY_SCOPE_AGENT);
        long long t0 = clock64();
        while (__hip_atomic_load(slot, __ATOMIC_RELAXED, __HIP_MEMORY_SCOPE_AGENT) < target) {
            __builtin_amdgcn_s_sleep(4);
            if (clock64() - t0 > 400000000LL) break;   // dead-man: fail loud, not hung
        }
    }
    __syncthreads();
}

// ---------------------------------------------------------------------------
// Persistent kernel: the serial T-loop. Block g owns h in [g*8, g*8+8).
// Wave w accumulates j-quarter w for all 8 rows (lane = batch), cross-wave
// K-reduction in LDS, wave w finalizes rows h = g*8 + {2w, 2w+1}.
// ---------------------------------------------------------------------------
__global__ __launch_bounds__(NTHR)
void rnn_loop_kernel(const float* __restrict__ X,
                     const float* __restrict__ hidden1,
                     const float* __restrict__ Wih,
                     const float* __restrict__ Whh,
                     float* __restrict__ hid_out)   // [T][B][NHID]
{
    __shared__ float sbuf[4][2][CJ * NB];     // staging: 4 waves x dbuf x 8KB = 64KB
    __shared__ float redbuf[4 * 8 * NB];      // K-reduction: 8KB
    __shared__ float sred2[8 * NB];           // hid_out transpose: 2KB
    __shared__ unsigned s_epoch;

    const int tid  = threadIdx.x;
    const int lane = tid & 63;
    const int w    = __builtin_amdgcn_readfirstlane(tid >> 6);
    const int g    = blockIdx.x;
    const int hq   = g * 8;                   // h-group base
    const int jq   = w * 256;                 // this wave's j-quarter base
    const int i0   = 2 * w, i1 = 2 * w + 1;   // rows this wave finalizes (local)
    const int h0   = hq + i0, h1 = hq + i1;

    // launch epoch (slot g touched only by block g => race-free, replay-safe)
    if (tid == 0) {
        unsigned e = __hip_atomic_load(&g_epochs[g], __ATOMIC_RELAXED, __HIP_MEMORY_SCOPE_AGENT) + 1;
        __hip_atomic_store(&g_epochs[g], e, __ATOMIC_RELAXED, __HIP_MEMORY_SCOPE_AGENT);
        s_epoch = e;
    }
    __syncthreads();
    const unsigned target = s_epoch * NWG;    // this launch's arrival target per slot

    // Whh row pointers (uniform => s_load path; L2 stays warm now: no more flushes)
    const float* wr0 = Whh + (size_t)(hq + 0) * NHID;
    const float* wr1 = Whh + (size_t)(hq + 1) * NHID;
    const float* wr2 = Whh + (size_t)(hq + 2) * NHID;
    const float* wr3 = Whh + (size_t)(hq + 3) * NHID;
    const float* wr4 = Whh + (size_t)(hq + 4) * NHID;
    const float* wr5 = Whh + (size_t)(hq + 5) * NHID;
    const float* wr6 = Whh + (size_t)(hq + 6) * NHID;
    const float* wr7 = Whh + (size_t)(hq + 7) * NHID;
    const float* wih0 = Wih + (size_t)h0 * NINP;
    const float* wih1 = Wih + (size_t)h1 * NINP;

    // persistent state x[b=lane][h0], x[b=lane][h1]
    float x0 = hidden1[(size_t)lane * NHID + h0];
    float x1 = hidden1[(size_t)lane * NHID + h1];
    float r0 = tanhf(x0);
    float r1 = tanhf(x1);
    __hip_atomic_store(&g_rT[(size_t)h0 * NB + lane], r0, __ATOMIC_RELAXED, __HIP_MEMORY_SCOPE_AGENT);
    __hip_atomic_store(&g_rT[(size_t)h1 * NB + lane], r1, __ATOMIC_RELAXED, __HIP_MEMORY_SCOPE_AGENT);
    grid_barrier(&g_bar[0], target, tid);

    int p = 0;
    for (int t = 0; t < TSTEPS; ++t) {
        const float* rsrc = g_rT + (size_t)p * NHID * NB;

        // stage chunk 0 of this wave's quarter (sc0|sc1: coherent read from L3)
        {
            const char* gsrc = (const char*)(rsrc + (size_t)jq * NB);
            char* lbase = (char*)&sbuf[w][0][0];
            #pragma unroll
            for (int q = 0; q < 8; ++q) {
                __builtin_amdgcn_global_load_lds(
                    (const __attribute__((address_space(1))) void*)(gsrc + q * 1024 + lane * 16),
                    (__attribute__((address_space(3))) void*)(lbase + q * 1024),
                    16, 0, AUX_COH);
            }
        }

        float a0 = 0.f, a1 = 0.f, a2 = 0.f, a3 = 0.f;
        float a4 = 0.f, a5 = 0.f, a6 = 0.f, a7 = 0.f;

        #pragma unroll 1   // keep staging/waitcnt structure intact
        for (int k = 0; k < NCH; ++k) {
            if (k + 1 < NCH) {
                const char* gsrc = (const char*)(rsrc + (size_t)(jq + (k + 1) * CJ) * NB);
                char* lbase = (char*)&sbuf[w][(k + 1) & 1][0];
                #pragma unroll
                for (int q = 0; q < 8; ++q) {
                    __builtin_amdgcn_global_load_lds(
                        (const __attribute__((address_space(1))) void*)(gsrc + q * 1024 + lane * 16),
                        (__attribute__((address_space(3))) void*)(lbase + q * 1024),
                        16, 0, AUX_COH);
                }
                asm volatile("s_waitcnt vmcnt(8)" ::: "memory");  // chunk k ready
            } else {
                asm volatile("s_waitcnt vmcnt(0)" ::: "memory");
            }

            const float* buf = &sbuf[w][k & 1][0];
            const int jb = jq + k * CJ;
            #pragma unroll 8
            for (int j = 0; j < CJ; ++j) {
                float rv = buf[j * NB + lane];     // ds_read_b32, 2-way alias (free)
                a0 = fmaf(wr0[jb + j], rv, a0);    // uniform -> s_load, warm L2
                a1 = fmaf(wr1[jb + j], rv, a1);
                a2 = fmaf(wr2[jb + j], rv, a2);
                a3 = fmaf(wr3[jb + j], rv, a3);
                a4 = fmaf(wr4[jb + j], rv, a4);
                a5 = fmaf(wr5[jb + j], rv, a5);
                a6 = fmaf(wr6[jb + j], rv, a6);
                a7 = fmaf(wr7[jb + j], rv, a7);
            }
        }

        // cross-wave K-reduction (this wave's staging drained: vmcnt(0) above)
        redbuf[(w * 8 + 0) * NB + lane] = a0;
        redbuf[(w * 8 + 1) * NB + lane] = a1;
        redbuf[(w * 8 + 2) * NB + lane] = a2;
        redbuf[(w * 8 + 3) * NB + lane] = a3;
        redbuf[(w * 8 + 4) * NB + lane] = a4;
        redbuf[(w * 8 + 5) * NB + lane] = a5;
        redbuf[(w * 8 + 6) * NB + lane] = a6;
        redbuf[(w * 8 + 7) * NB + lane] = a7;
        __syncthreads();
        float dot0 = redbuf[(0 * 8 + i0) * NB + lane] + redbuf[(1 * 8 + i0) * NB + lane]
                   + redbuf[(2 * 8 + i0) * NB + lane] + redbuf[(3 * 8 + i0) * NB + lane];
        float dot1 = redbuf[(0 * 8 + i1) * NB + lane] + redbuf[(1 * 8 + i1) * NB + lane]
                   + redbuf[(2 * 8 + i1) * NB + lane] + redbuf[(3 * 8 + i1) * NB + lane];

        // input projection (X row loaded once, reused for both rows)
        float xw0 = 0.f, xw1 = 0.f;
        const float4* xp = (const float4*)(X + ((size_t)t * NB + lane) * NINP);
        #pragma unroll
        for (int i = 0; i < NINP / 4; ++i) {
            float4 v = xp[i];
            xw0 = fmaf(wih0[4 * i + 0], v.x, xw0); xw1 = fmaf(wih1[4 * i + 0], v.x, xw1);
            xw0 = fmaf(wih0[4 * i + 1], v.y, xw0); xw1 = fmaf(wih1[4 * i + 1], v.y, xw1);
            xw0 = fmaf(wih0[4 * i + 2], v.z, xw0); xw1 = fmaf(wih1[4 * i + 2], v.z, xw1);
            xw0 = fmaf(wih0[4 * i + 3], v.w, xw0); xw1 = fmaf(wih1[4 * i + 3], v.w, xw1);
        }

        // leaky-integrator update + tanh (matches reference)
        x0 = fmaf(ALPHA_F, dot0 + xw0 - x0, x0);
        x1 = fmaf(ALPHA_F, dot1 + xw1 - x1, x1);
        r0 = tanhf(x0);
        r1 = tanhf(x1);

        // r for next step -> L3 (sc1 write-through; coalesced 64x4B)
        {
            float* rdst = g_rT + (size_t)(p ^ 1) * NHID * NB;
            __hip_atomic_store(&rdst[(size_t)h0 * NB + lane], r0, __ATOMIC_RELAXED, __HIP_MEMORY_SCOPE_AGENT);
            __hip_atomic_store(&rdst[(size_t)h1 * NB + lane], r1, __ATOMIC_RELAXED, __HIP_MEMORY_SCOPE_AGENT);
        }

        // hid_out: transpose through LDS, two dwordx4 stores per block
        sred2[i0 * NB + lane] = r0;
        sred2[i1 * NB + lane] = r1;
        __syncthreads();
        if (w < 2) {
            float4 v;
            v.x = sred2[(4 * w + 0) * NB + lane];
            v.y = sred2[(4 * w + 1) * NB + lane];
            v.z = sred2[(4 * w + 2) * NB + lane];
            v.w = sred2[(4 * w + 3) * NB + lane];
            *(float4*)(hid_out + ((size_t)t * NB + lane) * NHID + hq + 4 * w) = v;
        }

        grid_barrier(&g_bar[t + 1], target, tid);
        p ^= 1;
    }
}

// ---------------------------------------------------------------------------
// Parallel readout: one wave per (t,b). outv = r@Woutᵀ + bout; outp = pj@outv.
// ---------------------------------------------------------------------------
__global__ __launch_bounds__(256)
void out_proj_kernel(const float* __restrict__ hid,      // [T*B][NHID]
                     const float* __restrict__ perturb,  // [T*B][3][3]
                     const float* __restrict__ Wout,     // [3][NHID]
                     const float* __restrict__ bout,     // [3]
                     float* __restrict__ outv,           // [T*B][3]
                     float* __restrict__ outp)           // [T*B][3]
{
    const int gw   = (int)((blockIdx.x * blockDim.x + threadIdx.x) >> 6);
    const int lane = threadIdx.x & 63;
    if (gw >= TSTEPS * NB) return;

    const float4* r4  = (const float4*)(hid + (size_t)gw * NHID);
    const float4* w04 = (const float4*)(Wout);
    const float4* w14 = (const float4*)(Wout + NHID);
    const float4* w24 = (const float4*)(Wout + 2 * NHID);

    float s0 = 0.f, s1 = 0.f, s2 = 0.f;
    #pragma unroll
    for (int q = 0; q < 4; ++q) {
        int idx = lane * 4 + q;
        float4 v = r4[idx];
        float4 a = w04[idx]; s0 += v.x * a.x + v.y * a.y + v.z * a.z + v.w * a.w;
        float4 b = w14[idx]; s1 += v.x * b.x + v.y * b.y + v.z * b.z + v.w * b.w;
        float4 c = w24[idx]; s2 += v.x * c.x + v.y * c.y + v.z * c.z + v.w * c.w;
    }
    #pragma unroll
    for (int m = 1; m < 64; m <<= 1) {
        s0 += __shfl_xor(s0, m, 64);
        s1 += __shfl_xor(s1, m, 64);
        s2 += __shfl_xor(s2, m, 64);
    }
    if (lane == 0) {
        float o0 = s0 + bout[0];
        float o1 = s1 + bout[1];
        float o2 = s2 + bout[2];
        float* ov = outv + (size_t)gw * 3;
        ov[0] = o0; ov[1] = o1; ov[2] = o2;
        const float* pj = perturb + (size_t)gw * 9;
        float* op = outp + (size_t)gw * 3;
        op[0] = pj[0] * o0 + pj[1] * o1 + pj[2] * o2;
        op[1] = pj[3] * o0 + pj[4] * o1 + pj[5] * o2;
        op[2] = pj[6] * o0 + pj[7] * o1 + pj[8] * o2;
    }
}

// ---------------------------------------------------------------------------
extern "C" void kernel_launch(void* const* d_in, const int* in_sizes, int n_in,
                              void* d_out, int out_size, void* d_ws, size_t ws_size,
                              hipStream_t stream)
{
    const float* X       = (const float*)d_in[0];
    const float* perturb = (const float*)d_in[1];
    const float* hidden1 = (const float*)d_in[2];
    const float* Wih     = (const float*)d_in[3];
    const float* Whh     = (const float*)d_in[4];
    const float* Wout    = (const float*)d_in[5];
    const float* bout    = (const float*)d_in[6];

    float* out  = (float*)d_out;
    float* outv = out;
    float* outp = out + (size_t)TSTEPS * NB * NOUTV;                 // +96000
    float* hid  = out + (size_t)2 * TSTEPS * NB * NOUTV;             // +192000

    // cooperative launch only for the co-residency guarantee (128 blocks)
    void* args[] = { (void*)&X, (void*)&hidden1, (void*)&Wih, (void*)&Whh,
                     (void*)&hid };
    hipLaunchCooperativeKernel((void*)rnn_loop_kernel, dim3(NWG), dim3(NTHR),
                               args, 0, stream);

    out_proj_kernel<<<dim3((TSTEPS * NB) / 4), dim3(256), 0, stream>>>(
        hid, perturb, Wout, bout, outv, outp);
}